// Round 1
// baseline (145.088 us; speedup 1.0000x reference)
//
#include <hip/hip_runtime.h>
#include <math.h>

#define NV 16385
#define NEDGE 131072
#define NEG -1e30f
#define SCALE 2.8853900817779268f  // 2*log2(e): tanh(x) = 1 - 2/(exp2(SCALE*x)+1)

typedef __attribute__((ext_vector_type(8))) short short8;
typedef __attribute__((ext_vector_type(4))) float f32x4;

// Scratch as static device globals. All sync state reset by the finalizer
// block each launch (.bss-zero on first launch) -> graph replays identical.
__device__ float g_part[4 * NEDGE];  // per-h-tile partial edge sums
__device__ float g_mats[32 * 64];    // 32 segment matrices (8x8, row-major)
__device__ float g_gold;             // gold-path sum
__device__ int g_cnt[32];            // per-segment producer tickets (32 each)
__device__ int g_done;               // tail-block completion ticket

__device__ __forceinline__ unsigned short f2bf(float x) {
  union { float f; unsigned int u; } c; c.f = x;
  unsigned int u = c.u;
  unsigned int r = (u + 0x7fffu + ((u >> 16) & 1u)) >> 16;  // RNE
  return (unsigned short)r;
}

__device__ __forceinline__ float lse8(float x0, float x1, float x2, float x3,
                                      float x4, float x5, float x6, float x7) {
  float m = fmaxf(fmaxf(fmaxf(x0, x1), fmaxf(x2, x3)),
                  fmaxf(fmaxf(x4, x5), fmaxf(x6, x7)));
  float s = __expf(x0 - m) + __expf(x1 - m) + __expf(x2 - m) + __expf(x3 - m) +
            __expf(x4 - m) + __expf(x5 - m) + __expf(x6 - m) + __expf(x7 - m);
  return m + __logf(s);
}

// Full-wave 8x8 log-semiring matmul: lane l=(i*8+j) holds A[i][j], B[i][j];
// returns (A (X) B)[i][j] = lse_k(A[i][k] + B[k][j]).  A = later chunk.
__device__ __forceinline__ float comb8(float A, float B, int i8, int j) {
  float x0 = __shfl(A, i8 + 0) + __shfl(B, 0 + j);
  float x1 = __shfl(A, i8 + 1) + __shfl(B, 8 + j);
  float x2 = __shfl(A, i8 + 2) + __shfl(B, 16 + j);
  float x3 = __shfl(A, i8 + 3) + __shfl(B, 24 + j);
  float x4 = __shfl(A, i8 + 4) + __shfl(B, 32 + j);
  float x5 = __shfl(A, i8 + 5) + __shfl(B, 40 + j);
  float x6 = __shfl(A, i8 + 6) + __shfl(B, 48 + j);
  float x7 = __shfl(A, i8 + 7) + __shfl(B, 56 + j);
  return lse8(x0, x1, x2, x3, x4, x5, x6, x7);
}

// One edge-phase term with FACTORED exponential: ea/eb are exp2-domain values
// (ea*eb = exp2(2log2e*(A+B+b1))).  acc += w * rcp(ea*eb + 1); only 1 trans op.
#define ETERM(ea, eb, w, acc)                              \
  {                                                        \
    float e_ = (ea) * (eb);                                \
    acc = fmaf(__builtin_amdgcn_rcpf(e_ + 1.f), (w), acc); \
  }

// Fully fused kernel. Blocks [0,1024): k12 producer body (4 h-tiles x 256
// node-tiles of 64). Blocks [1024,1056): tail segment blocks, each acquire-
// spins on its 32 producers, then the last tail block does the final combine.
__global__ __launch_bounds__(256, 4) void k_all(const float* __restrict__ emb,
                                                const float* __restrict__ W1,
                                                const float* __restrict__ b1,
                                                const float* __restrict__ W2,
                                                const float* __restrict__ b2,
                                                float* __restrict__ out) {
  __shared__ __align__(16) unsigned short lds[19728];  // 38.5 KB
  const int t = threadIdx.x;
  const int bid = blockIdx.x;

  if (bid < 1024) {
    // ------------------- producer: k12_fused body -------------------
    unsigned short* Es = lds;             // [80][136] u16 emb tile (phase 1)
    float* CA = (float*)lds;              // [80][68] f32 EA (aliases Es)
    float* CB = (float*)(lds + 10880);    // [64][68] f32 EB
    float* W2s = (float*)(lds + 19584);   // [64] f32 (-2*W2)
    float* Wsum = (float*)(lds + 19712);  // [8] per-granule sum

    const int hx = bid & 3;
    const int by = bid >> 2;
    const int h0 = hx << 6;
    const int i0 = by << 6;
    const int wv = t >> 6, lane = t & 63;
    const int l15 = lane & 15, quad = lane >> 4;
    const int colh = h0 + (wv << 4) + l15;

    if (t < 64) W2s[t] = -2.f * W2[h0 + t];
    if (t < 8) {
      float s = 0.f;
#pragma unroll
      for (int jj = 0; jj < 8; ++jj) s += W2[h0 + (t << 3) + jj];
      Wsum[t] = s;
    }

    // Stage emb rows [i0-7, i0+73) x all 128 k -> bf16. 80 rows x 32 float4.
#pragma unroll
    for (int it = 0; it < 10; ++it) {
      int idx = t + (it << 8);
      int row = idx >> 5;
      int k4 = (idx & 31) << 2;
      int v = i0 - 7 + row;
      float4 g = make_float4(0.f, 0.f, 0.f, 0.f);
      if (v >= 0 && v < NV) g = *(const float4*)&emb[v * 128 + k4];
      uint2 pk;
      pk.x = f2bf(g.x) | ((unsigned int)f2bf(g.y) << 16);
      pk.y = f2bf(g.z) | ((unsigned int)f2bf(g.w) << 16);
      *(uint2*)&Es[row * 136 + k4] = pk;
    }

    f32x4 accA[5], accB[4];
#pragma unroll
    for (int m = 0; m < 5; ++m) accA[m] = (f32x4){0.f, 0.f, 0.f, 0.f};
#pragma unroll
    for (int m = 0; m < 4; ++m) accB[m] = (f32x4){0.f, 0.f, 0.f, 0.f};

    // W1 fragments straight from global (L2-hot): frag kc -> k = kc*32+quad*8+i.
    short8 fA[4], fB[4];
#pragma unroll
    for (int kc = 0; kc < 4; ++kc) {
      const int kb = (kc << 5) + (quad << 3);
#pragma unroll
      for (int i = 0; i < 8; i += 2) {
        float a0 = W1[(kb + i) * 256 + colh];
        float a1 = W1[(kb + i + 1) * 256 + colh];
        float c0 = W1[(128 + kb + i) * 256 + colh];
        float c1 = W1[(128 + kb + i + 1) * 256 + colh];
        ((unsigned int*)&fA[kc])[i >> 1] = f2bf(a0) | ((unsigned int)f2bf(a1) << 16);
        ((unsigned int*)&fB[kc])[i >> 1] = f2bf(c0) | ((unsigned int)f2bf(c1) << 16);
      }
    }
    __syncthreads();

#pragma unroll
    for (int kc = 0; kc < 4; ++kc) {
      const int kbase = (kc << 5) + (quad << 3);
#pragma unroll
      for (int mf = 0; mf < 5; ++mf) {
        short8 a = *(const short8*)&Es[((mf << 4) + l15) * 136 + kbase];
        accA[mf] = __builtin_amdgcn_mfma_f32_16x16x32_bf16(a, fA[kc], accA[mf], 0, 0, 0);
      }
#pragma unroll
      for (int mf = 0; mf < 4; ++mf) {
        short8 a = *(const short8*)&Es[(8 + (mf << 4) + l15) * 136 + kbase];
        accB[mf] = __builtin_amdgcn_mfma_f32_16x16x32_bf16(a, fB[kc], accB[mf], 0, 0, 0);
      }
    }
    __syncthreads();  // all MFMA reads of Es done before aliasing C over it
    // Store C tiles in exp2 domain: EA = exp2(SCALE*(A+b1)), EB = exp2(SCALE*B).
    // C/D frag: row = quad*4+reg, col = lane&15.  Pitch 68: 2-way (free).
    const int hcol = (wv << 4) + l15;
    const float b1s = b1[h0 + hcol];
#pragma unroll
    for (int mf = 0; mf < 5; ++mf) {
      int rb = (mf << 4) + (quad << 2);
#pragma unroll
      for (int rr = 0; rr < 4; ++rr)
        CA[(rb + rr) * 68 + hcol] =
            __builtin_amdgcn_exp2f((accA[mf][rr] + b1s) * SCALE);
    }
#pragma unroll
    for (int mf = 0; mf < 4; ++mf) {
      int rb = (mf << 4) + (quad << 2);
#pragma unroll
      for (int rr = 0; rr < 4; ++rr)
        CB[(rb + rr) * 68 + hcol] = __builtin_amdgcn_exp2f(accB[mf][rr] * SCALE);
    }
    __syncthreads();
    // Edge phase: thread t -> k = t&7, qb = t>>3; edges q = qb, qb+32.
    const int k = t & 7;
    const int qb = t >> 3;
    float ws_all = 0.f;
#pragma unroll
    for (int s = 0; s < 8; ++s) ws_all += Wsum[s];
    float pa0 = 0.f, pa1 = 0.f, pb0 = 0.f, pb1 = 0.f;
#pragma unroll
    for (int g = 0; g < 8; ++g) {
      const int s = (g + (k << 1)) & 7;  // granule rotation: uniform banks
      const float* wp = &W2s[s << 3];
      float4 w0 = *(const float4*)wp;
      float4 w1 = *(const float4*)(wp + 4);
      {
        const float* ap = &CA[(7 + qb - k) * 68 + (s << 3)];
        const float* bp = &CB[qb * 68 + (s << 3)];
        float4 a0 = *(const float4*)ap, a1 = *(const float4*)(ap + 4);
        float4 b0 = *(const float4*)bp, b1v = *(const float4*)(bp + 4);
        ETERM(a0.x, b0.x, w0.x, pa0); ETERM(a0.y, b0.y, w0.y, pa0);
        ETERM(a0.z, b0.z, w0.z, pa0); ETERM(a0.w, b0.w, w0.w, pa0);
        ETERM(a1.x, b1v.x, w1.x, pa1); ETERM(a1.y, b1v.y, w1.y, pa1);
        ETERM(a1.z, b1v.z, w1.z, pa1); ETERM(a1.w, b1v.w, w1.w, pa1);
      }
      {
        const int q = qb + 32;
        const float* ap = &CA[(7 + q - k) * 68 + (s << 3)];
        const float* bp = &CB[q * 68 + (s << 3)];
        float4 a0 = *(const float4*)ap, a1 = *(const float4*)(ap + 4);
        float4 b0 = *(const float4*)bp, b1v = *(const float4*)(bp + 4);
        ETERM(a0.x, b0.x, w0.x, pb0); ETERM(a0.y, b0.y, w0.y, pb0);
        ETERM(a0.z, b0.z, w0.z, pb0); ETERM(a0.w, b0.w, w0.w, pb0);
        ETERM(a1.x, b1v.x, w1.x, pb1); ETERM(a1.y, b1v.y, w1.y, pb1);
        ETERM(a1.z, b1v.z, w1.z, pb1); ETERM(a1.w, b1v.w, w1.w, pb1);
      }
    }
    const int ebase = hx * NEDGE + (by << 9) + t;
    g_part[ebase] = (pa0 + pa1) + ws_all;
    g_part[ebase + 256] = (pb0 + pb1) + ws_all;
    // Publish this block's g_part slice: release to device scope, then tick
    // the segment counter the consuming tail block spins on.
    __syncthreads();
    if (t == 0) {
      __threadfence();
      __hip_atomic_fetch_add(&g_cnt[by >> 3], 1, __ATOMIC_RELEASE,
                             __HIP_MEMORY_SCOPE_AGENT);
    }
    return;
  }

  // ------------------- tail: k_tail1 (+ fused k_tail2 on last block) -------
  const int tb = bid - 1024;  // segment id [0,32)
  float* wf = (float*)lds;            // [64][64]  (16 KB)
  float* m8 = (float*)(lds + 8192);   // [8][64]   (2 KB, byte 16384)
  float* l2m = (float*)(lds + 9216);  // [4][64]   (1 KB, byte 18432)
  int* flag = (int*)(lds + 9728);     // finalizer-election flag (byte 19456)

  // Wait for this segment's 32 producer blocks (4 h-tiles x 8 node-tiles).
  if (t == 0) {
    while (__hip_atomic_load(&g_cnt[tb], __ATOMIC_ACQUIRE,
                             __HIP_MEMORY_SCOPE_AGENT) < 32)
      __builtin_amdgcn_s_sleep(2);
  }
  __syncthreads();
  __threadfence();  // acquire side: invalidate stale L1/L2 before g_part reads

  const float b2v = b2[0];
  float gold = 0.f;
#pragma unroll
  for (int it = 0; it < 4; ++it) {
    const int e4 = t + (it << 8);
    const int gidx = (tb << 10) + e4;
    float4 s0 = *(const float4*)&g_part[gidx << 2];
    float4 s1 = *(const float4*)&g_part[NEDGE + (gidx << 2)];
    float4 s2 = *(const float4*)&g_part[2 * NEDGE + (gidx << 2)];
    float4 s3 = *(const float4*)&g_part[3 * NEDGE + (gidx << 2)];
    float d0 = s0.x + s1.x + s2.x + s3.x + b2v;
    float d1 = s0.y + s1.y + s2.y + s3.y + b2v;
    float d2 = s0.z + s1.z + s2.z + s3.z + b2v;
    float d3 = s0.w + s1.w + s2.w + s3.w + b2v;
    d0 = fmaxf(d0, 0.f) + log1pf(__expf(-fabsf(d0)));
    d1 = fmaxf(d1, 0.f) + log1pf(__expf(-fabsf(d1)));
    d2 = fmaxf(d2, 0.f) + log1pf(__expf(-fabsf(d2)));
    d3 = fmaxf(d3, 0.f) + log1pf(__expf(-fabsf(d3)));
    const int q = e4 << 2;
    const int cl = q >> 9, r = q & 511;
    const int s = r >> 3, kk = r & 7;
    *(float4*)&wf[s * 64 + (cl << 3) + kk] = make_float4(d0, d1, d2, d3);
    if ((t & 1) == 0) gold += d0;  // k==0 edges (gold path)
  }
  // Gold: butterfly within wave, one atomic per wave (4/block, 128 total).
#pragma unroll
  for (int off = 32; off > 0; off >>= 1) gold += __shfl_xor(gold, off, 64);
  if ((t & 63) == 0) atomicAdd(&g_gold, gold);
  __syncthreads();
  if (tb == 0 && t == 0) {
    // node i = s+1 has valid preds kk <= s only: poison invalid d with +1e30
    for (int s = 0; s < 7; ++s)
      for (int kk = s + 1; kk < 8; ++kk) wf[s * 64 + kk] = 1e30f;
  }
  __syncthreads();
  if (t < 64) {  // wave 0: 8 chunk recurrences (8 lanes each)
    const int g = t >> 3, j = t & 7;
    float P[8];
#pragma unroll
    for (int kk = 0; kk < 8; ++kk) P[kk] = (kk == j) ? 0.f : NEG;
    for (int s = 0; s < 64; ++s) {
      const float* wp = &wf[s * 64 + (g << 3)];
      float4 wa = *(const float4*)wp;
      float4 wb = *(const float4*)(wp + 4);
      float nv = lse8(P[0] - wa.x, P[1] - wa.y, P[2] - wa.z, P[3] - wa.w,
                      P[4] - wb.x, P[5] - wb.y, P[6] - wb.z, P[7] - wb.w);
#pragma unroll
      for (int kk = 7; kk > 0; --kk) P[kk] = P[kk - 1];
      P[0] = nv;
    }
#pragma unroll
    for (int kk = 0; kk < 8; ++kk) m8[g * 64 + (kk << 3) + j] = P[kk];
    // Combine 8 chunk mats -> segment mat (in-wave, DS ops in-order).
    const int i8 = (t >> 3) << 3;
    float R = m8[t];
#pragma unroll
    for (int g2 = 1; g2 < 8; ++g2) R = comb8(m8[g2 * 64 + t], R, i8, j);
    g_mats[(tb << 6) + t] = R;
  }
  __syncthreads();
  // Elect the last-finishing tail block as finalizer (fused k_tail2).
  if (t == 0) {
    __threadfence();
    int old = __hip_atomic_fetch_add(&g_done, 1, __ATOMIC_ACQ_REL,
                                     __HIP_MEMORY_SCOPE_AGENT);
    flag[0] = (old == 31) ? 1 : 0;
  }
  __syncthreads();
  if (flag[0]) {
    __threadfence();  // acquire: other blocks' g_mats + g_gold now visible
    const int l = t & 63, w = t >> 6;
    const int i8 = (l >> 3) << 3, j = l & 7;
    float G = g_mats[((w << 3) << 6) + l];
#pragma unroll
    for (int s2 = 1; s2 < 8; ++s2)
      G = comb8(g_mats[(((w << 3) + s2) << 6) + l], G, i8, j);
    l2m[w * 64 + l] = G;
    __syncthreads();
    if (t < 64) {
      float G2 = l2m[t];
#pragma unroll
      for (int w2 = 1; w2 < 4; ++w2) G2 = comb8(l2m[w2 * 64 + t], G2, i8, j);
      if (t == 0) {
        out[0] = __hip_atomic_load(&g_gold, __ATOMIC_RELAXED,
                                   __HIP_MEMORY_SCOPE_AGENT) + G2;
        g_gold = 0.f;  // reset for next launch / graph replay
        g_done = 0;
      }
    }
    if (t < 32) g_cnt[t] = 0;  // all tail blocks already past their spin
  }
}

extern "C" void kernel_launch(void* const* d_in, const int* in_sizes, int n_in,
                              void* d_out, int out_size, void* d_ws, size_t ws_size,
                              hipStream_t stream) {
  const float* emb = (const float*)d_in[0];
  const float* W1 = (const float*)d_in[1];
  const float* b1 = (const float*)d_in[2];
  const float* W2 = (const float*)d_in[3];
  const float* b2 = (const float*)d_in[4];
  float* out = (float*)d_out;
  hipLaunchKernelGGL(k_all, dim3(1056), dim3(256), 0, stream, emb, W1, b1, W2, b2, out);
}

// Round 2
// 126.757 us; speedup vs baseline: 1.1446x; 1.1446x over previous
//
#include <hip/hip_runtime.h>
#include <math.h>

#define NV 16385
#define NEDGE 131072
#define NEG -1e30f
#define SCALE 2.8853900817779268f  // 2*log2(e): tanh(x) = 1 - 2/(exp2(SCALE*x)+1)

typedef __attribute__((ext_vector_type(8))) short short8;
typedef __attribute__((ext_vector_type(4))) float f32x4;

// Scratch as static device globals. All sync state reset by the finalizer
// block each launch (.bss-zero on first launch) -> graph replays identical.
__device__ float g_part[4 * NEDGE];  // per-h-tile partial edge sums
__device__ float g_mats[32 * 64];    // 32 segment matrices (8x8, row-major)
__device__ float g_gold;             // gold-path sum
__device__ int g_cnt[32];            // per-segment producer tickets (32 each)
__device__ int g_done;               // segment-tail completion ticket

__device__ __forceinline__ unsigned short f2bf(float x) {
  union { float f; unsigned int u; } c; c.f = x;
  unsigned int u = c.u;
  unsigned int r = (u + 0x7fffu + ((u >> 16) & 1u)) >> 16;  // RNE
  return (unsigned short)r;
}

__device__ __forceinline__ float lse8(float x0, float x1, float x2, float x3,
                                      float x4, float x5, float x6, float x7) {
  float m = fmaxf(fmaxf(fmaxf(x0, x1), fmaxf(x2, x3)),
                  fmaxf(fmaxf(x4, x5), fmaxf(x6, x7)));
  float s = __expf(x0 - m) + __expf(x1 - m) + __expf(x2 - m) + __expf(x3 - m) +
            __expf(x4 - m) + __expf(x5 - m) + __expf(x6 - m) + __expf(x7 - m);
  return m + __logf(s);
}

// Full-wave 8x8 log-semiring matmul: lane l=(i*8+j) holds A[i][j], B[i][j];
// returns (A (X) B)[i][j] = lse_k(A[i][k] + B[k][j]).  A = later chunk.
__device__ __forceinline__ float comb8(float A, float B, int i8, int j) {
  float x0 = __shfl(A, i8 + 0) + __shfl(B, 0 + j);
  float x1 = __shfl(A, i8 + 1) + __shfl(B, 8 + j);
  float x2 = __shfl(A, i8 + 2) + __shfl(B, 16 + j);
  float x3 = __shfl(A, i8 + 3) + __shfl(B, 24 + j);
  float x4 = __shfl(A, i8 + 4) + __shfl(B, 32 + j);
  float x5 = __shfl(A, i8 + 5) + __shfl(B, 40 + j);
  float x6 = __shfl(A, i8 + 6) + __shfl(B, 48 + j);
  float x7 = __shfl(A, i8 + 7) + __shfl(B, 56 + j);
  return lse8(x0, x1, x2, x3, x4, x5, x6, x7);
}

// One edge-phase term with FACTORED exponential: ea/eb are exp2-domain values
// (ea*eb = exp2(2log2e*(A+B+b1))).  acc += w * rcp(ea*eb + 1); only 1 trans op.
#define ETERM(ea, eb, w, acc)                              \
  {                                                        \
    float e_ = (ea) * (eb);                                \
    acc = fmaf(__builtin_amdgcn_rcpf(e_ + 1.f), (w), acc); \
  }

// Fused kernel, grid = exactly 1024 producer blocks (4 h-tiles x 256 node
// tiles). NO dedicated tail blocks: the 32nd finisher of each 8-node-tile
// segment is elected (ticket fetch_add) to run that segment's recurrence
// in-place; the 32nd segment-finisher runs the final combine. Producers
// publish g_part with write-through (sc1) agent-scope stores, so NO
// wbl2/inv cache maintenance runs in the producer path; only the 32
// electees + 1 finalizer each issue a single acquire (buffer_inv).
__global__ __launch_bounds__(256, 4) void k_all(const float* __restrict__ emb,
                                                const float* __restrict__ W1,
                                                const float* __restrict__ b1,
                                                const float* __restrict__ W2,
                                                const float* __restrict__ b2,
                                                float* __restrict__ out) {
  __shared__ __align__(16) unsigned short lds[19728];  // 38.5 KB
  const int t = threadIdx.x;
  const int bid = blockIdx.x;

  // ------------------- producer phase -------------------
  unsigned short* Es = lds;             // [80][136] u16 emb tile (phase 1)
  float* CA = (float*)lds;              // [80][68] f32 EA (aliases Es)
  float* CB = (float*)(lds + 10880);    // [64][68] f32 EB (byte 21760)
  float* W2s = (float*)(lds + 19584);   // [64] f32 (-2*W2)   (byte 39168)
  float* Wsum = (float*)(lds + 19712);  // [8] per-granule sum (byte 39424)

  const int hx = bid & 3;
  const int by = bid >> 2;
  const int h0 = hx << 6;
  const int i0 = by << 6;
  const int wv = t >> 6, lane = t & 63;
  const int l15 = lane & 15, quad = lane >> 4;
  const int colh = h0 + (wv << 4) + l15;

  if (t < 64) W2s[t] = -2.f * W2[h0 + t];
  if (t < 8) {
    float s = 0.f;
#pragma unroll
    for (int jj = 0; jj < 8; ++jj) s += W2[h0 + (t << 3) + jj];
    Wsum[t] = s;
  }

  // Stage emb rows [i0-7, i0+73) x all 128 k -> bf16. 80 rows x 32 float4.
#pragma unroll
  for (int it = 0; it < 10; ++it) {
    int idx = t + (it << 8);
    int row = idx >> 5;
    int k4 = (idx & 31) << 2;
    int v = i0 - 7 + row;
    float4 g = make_float4(0.f, 0.f, 0.f, 0.f);
    if (v >= 0 && v < NV) g = *(const float4*)&emb[v * 128 + k4];
    uint2 pk;
    pk.x = f2bf(g.x) | ((unsigned int)f2bf(g.y) << 16);
    pk.y = f2bf(g.z) | ((unsigned int)f2bf(g.w) << 16);
    *(uint2*)&Es[row * 136 + k4] = pk;
  }

  f32x4 accA[5], accB[4];
#pragma unroll
  for (int m = 0; m < 5; ++m) accA[m] = (f32x4){0.f, 0.f, 0.f, 0.f};
#pragma unroll
  for (int m = 0; m < 4; ++m) accB[m] = (f32x4){0.f, 0.f, 0.f, 0.f};

  // W1 fragments straight from global (L2-hot): frag kc -> k = kc*32+quad*8+i.
  short8 fA[4], fB[4];
#pragma unroll
  for (int kc = 0; kc < 4; ++kc) {
    const int kb = (kc << 5) + (quad << 3);
#pragma unroll
    for (int i = 0; i < 8; i += 2) {
      float a0 = W1[(kb + i) * 256 + colh];
      float a1 = W1[(kb + i + 1) * 256 + colh];
      float c0 = W1[(128 + kb + i) * 256 + colh];
      float c1 = W1[(128 + kb + i + 1) * 256 + colh];
      ((unsigned int*)&fA[kc])[i >> 1] = f2bf(a0) | ((unsigned int)f2bf(a1) << 16);
      ((unsigned int*)&fB[kc])[i >> 1] = f2bf(c0) | ((unsigned int)f2bf(c1) << 16);
    }
  }
  __syncthreads();

#pragma unroll
  for (int kc = 0; kc < 4; ++kc) {
    const int kbase = (kc << 5) + (quad << 3);
#pragma unroll
    for (int mf = 0; mf < 5; ++mf) {
      short8 a = *(const short8*)&Es[((mf << 4) + l15) * 136 + kbase];
      accA[mf] = __builtin_amdgcn_mfma_f32_16x16x32_bf16(a, fA[kc], accA[mf], 0, 0, 0);
    }
#pragma unroll
    for (int mf = 0; mf < 4; ++mf) {
      short8 a = *(const short8*)&Es[(8 + (mf << 4) + l15) * 136 + kbase];
      accB[mf] = __builtin_amdgcn_mfma_f32_16x16x32_bf16(a, fB[kc], accB[mf], 0, 0, 0);
    }
  }
  __syncthreads();  // all MFMA reads of Es done before aliasing C over it
  // Store C tiles in exp2 domain: EA = exp2(SCALE*(A+b1)), EB = exp2(SCALE*B).
  // C/D frag: row = quad*4+reg, col = lane&15.  Pitch 68: 2-way (free).
  const int hcol = (wv << 4) + l15;
  const float b1s = b1[h0 + hcol];
#pragma unroll
  for (int mf = 0; mf < 5; ++mf) {
    int rb = (mf << 4) + (quad << 2);
#pragma unroll
    for (int rr = 0; rr < 4; ++rr)
      CA[(rb + rr) * 68 + hcol] =
          __builtin_amdgcn_exp2f((accA[mf][rr] + b1s) * SCALE);
  }
#pragma unroll
  for (int mf = 0; mf < 4; ++mf) {
    int rb = (mf << 4) + (quad << 2);
#pragma unroll
    for (int rr = 0; rr < 4; ++rr)
      CB[(rb + rr) * 68 + hcol] = __builtin_amdgcn_exp2f(accB[mf][rr] * SCALE);
  }
  __syncthreads();
  // Edge phase: thread t -> k = t&7, qb = t>>3; edges q = qb, qb+32.
  const int k = t & 7;
  const int qb = t >> 3;
  float ws_all = 0.f;
#pragma unroll
  for (int s = 0; s < 8; ++s) ws_all += Wsum[s];
  float pa0 = 0.f, pa1 = 0.f, pb0 = 0.f, pb1 = 0.f;
#pragma unroll
  for (int g = 0; g < 8; ++g) {
    const int s = (g + (k << 1)) & 7;  // granule rotation: uniform banks
    const float* wp = &W2s[s << 3];
    float4 w0 = *(const float4*)wp;
    float4 w1 = *(const float4*)(wp + 4);
    {
      const float* ap = &CA[(7 + qb - k) * 68 + (s << 3)];
      const float* bp = &CB[qb * 68 + (s << 3)];
      float4 a0 = *(const float4*)ap, a1 = *(const float4*)(ap + 4);
      float4 b0 = *(const float4*)bp, b1v = *(const float4*)(bp + 4);
      ETERM(a0.x, b0.x, w0.x, pa0); ETERM(a0.y, b0.y, w0.y, pa0);
      ETERM(a0.z, b0.z, w0.z, pa0); ETERM(a0.w, b0.w, w0.w, pa0);
      ETERM(a1.x, b1v.x, w1.x, pa1); ETERM(a1.y, b1v.y, w1.y, pa1);
      ETERM(a1.z, b1v.z, w1.z, pa1); ETERM(a1.w, b1v.w, w1.w, pa1);
    }
    {
      const int q = qb + 32;
      const float* ap = &CA[(7 + q - k) * 68 + (s << 3)];
      const float* bp = &CB[q * 68 + (s << 3)];
      float4 a0 = *(const float4*)ap, a1 = *(const float4*)(ap + 4);
      float4 b0 = *(const float4*)bp, b1v = *(const float4*)(bp + 4);
      ETERM(a0.x, b0.x, w0.x, pb0); ETERM(a0.y, b0.y, w0.y, pb0);
      ETERM(a0.z, b0.z, w0.z, pb0); ETERM(a0.w, b0.w, w0.w, pb0);
      ETERM(a1.x, b1v.x, w1.x, pb1); ETERM(a1.y, b1v.y, w1.y, pb1);
      ETERM(a1.z, b1v.z, w1.z, pb1); ETERM(a1.w, b1v.w, w1.w, pb1);
    }
  }
  const int ebase = hx * NEDGE + (by << 9) + t;
  // Publish via write-through agent-scope stores: lands at the coherence
  // point directly, so no wbl2/inv fence is needed in the producer path.
  __hip_atomic_store(&g_part[ebase], (pa0 + pa1) + ws_all,
                     __ATOMIC_RELAXED, __HIP_MEMORY_SCOPE_AGENT);
  __hip_atomic_store(&g_part[ebase + 256], (pb0 + pb1) + ws_all,
                     __ATOMIC_RELAXED, __HIP_MEMORY_SCOPE_AGENT);
  __syncthreads();  // drains vmcnt for every wave -> stores at coherence point

  int* flag = (int*)(lds + 9728);  // byte 19456 (CA region, now dead)
  const int seg = by >> 3;         // segment id [0,32)
  if (t == 0) {
    int old = __hip_atomic_fetch_add(&g_cnt[seg], 1, __ATOMIC_RELAXED,
                                     __HIP_MEMORY_SCOPE_AGENT);
    flag[0] = (old == 31);  // elect the segment's last finisher
  }
  __syncthreads();
  if (!flag[0]) return;  // 992 blocks end here

  // ------------------- segment tail (one block per segment) -------------
  // Single acquire: buffer_inv clears any stale L2 lines before g_part reads.
  if (t == 0)
    (void)__hip_atomic_load(&g_cnt[seg], __ATOMIC_ACQUIRE,
                            __HIP_MEMORY_SCOPE_AGENT);
  __syncthreads();

  float* wf = (float*)lds;            // [64][64]  (16 KB)
  float* m8 = (float*)(lds + 8192);   // [8][64]   (byte 16384)
  float* l2m = (float*)(lds + 9216);  // [4][64]   (byte 18432)

  const float b2v = b2[0];
  float gold = 0.f;
#pragma unroll
  for (int it = 0; it < 4; ++it) {
    const int e4 = t + (it << 8);
    const int gidx = (seg << 10) + e4;
    float4 s0 = *(const float4*)&g_part[gidx << 2];
    float4 s1 = *(const float4*)&g_part[NEDGE + (gidx << 2)];
    float4 s2 = *(const float4*)&g_part[2 * NEDGE + (gidx << 2)];
    float4 s3 = *(const float4*)&g_part[3 * NEDGE + (gidx << 2)];
    float d0 = s0.x + s1.x + s2.x + s3.x + b2v;
    float d1 = s0.y + s1.y + s2.y + s3.y + b2v;
    float d2 = s0.z + s1.z + s2.z + s3.z + b2v;
    float d3 = s0.w + s1.w + s2.w + s3.w + b2v;
    d0 = fmaxf(d0, 0.f) + log1pf(__expf(-fabsf(d0)));
    d1 = fmaxf(d1, 0.f) + log1pf(__expf(-fabsf(d1)));
    d2 = fmaxf(d2, 0.f) + log1pf(__expf(-fabsf(d2)));
    d3 = fmaxf(d3, 0.f) + log1pf(__expf(-fabsf(d3)));
    const int q = e4 << 2;
    const int cl = q >> 9, r = q & 511;
    const int s = r >> 3, kk = r & 7;
    *(float4*)&wf[s * 64 + (cl << 3) + kk] = make_float4(d0, d1, d2, d3);
    if ((t & 1) == 0) gold += d0;  // k==0 edges (gold path)
  }
  // Gold: butterfly within wave, one atomic per wave (4/block, 128 total).
#pragma unroll
  for (int off = 32; off > 0; off >>= 1) gold += __shfl_xor(gold, off, 64);
  if ((t & 63) == 0) atomicAdd(&g_gold, gold);
  __syncthreads();
  if (seg == 0 && t == 0) {
    // node i = s+1 has valid preds kk <= s only: poison invalid d with +1e30
    for (int s = 0; s < 7; ++s)
      for (int kk = s + 1; kk < 8; ++kk) wf[s * 64 + kk] = 1e30f;
  }
  __syncthreads();
  if (t < 64) {  // wave 0: 8 chunk recurrences (8 lanes each)
    const int g = t >> 3, j = t & 7;
    float P[8];
#pragma unroll
    for (int kk = 0; kk < 8; ++kk) P[kk] = (kk == j) ? 0.f : NEG;
    for (int s = 0; s < 64; ++s) {
      const float* wp = &wf[s * 64 + (g << 3)];
      float4 wa = *(const float4*)wp;
      float4 wb = *(const float4*)(wp + 4);
      float nv = lse8(P[0] - wa.x, P[1] - wa.y, P[2] - wa.z, P[3] - wa.w,
                      P[4] - wb.x, P[5] - wb.y, P[6] - wb.z, P[7] - wb.w);
#pragma unroll
      for (int kk = 7; kk > 0; --kk) P[kk] = P[kk - 1];
      P[0] = nv;
    }
#pragma unroll
    for (int kk = 0; kk < 8; ++kk) m8[g * 64 + (kk << 3) + j] = P[kk];
    // Combine 8 chunk mats -> segment mat (in-wave, DS ops in-order).
    const int i8 = (t >> 3) << 3;
    const int jj = t & 7;
    float R = m8[t];
#pragma unroll
    for (int g2 = 1; g2 < 8; ++g2) R = comb8(m8[g2 * 64 + t], R, i8, jj);
    // Write-through publish of this segment's matrix.
    __hip_atomic_store(&g_mats[(seg << 6) + t], R, __ATOMIC_RELAXED,
                       __HIP_MEMORY_SCOPE_AGENT);
  }
  __syncthreads();  // drain wave0's g_mats stores (+ earlier gold atomics)
  if (t == 0) {
    int old2 = __hip_atomic_fetch_add(&g_done, 1, __ATOMIC_RELAXED,
                                      __HIP_MEMORY_SCOPE_AGENT);
    flag[1] = (old2 == 31);
  }
  __syncthreads();
  if (!flag[1]) return;  // 31 segment tails end here

  // ------------------- finalizer (last segment tail) -------------------
  if (t == 0)
    (void)__hip_atomic_load(&g_done, __ATOMIC_ACQUIRE,
                            __HIP_MEMORY_SCOPE_AGENT);  // buffer_inv
  __syncthreads();
  {
    const int l = t & 63, w = t >> 6;
    const int i8 = (l >> 3) << 3, j = l & 7;
    float G = g_mats[((w << 3) << 6) + l];
#pragma unroll
    for (int s2 = 1; s2 < 8; ++s2)
      G = comb8(g_mats[(((w << 3) + s2) << 6) + l], G, i8, j);
    l2m[w * 64 + l] = G;
    __syncthreads();
    if (t < 64) {
      float G2 = l2m[t];
#pragma unroll
      for (int w2 = 1; w2 < 4; ++w2) G2 = comb8(l2m[w2 * 64 + t], G2, i8, j);
      if (t == 0) {
        float gg = __hip_atomic_load(&g_gold, __ATOMIC_RELAXED,
                                     __HIP_MEMORY_SCOPE_AGENT);
        out[0] = gg + G2;  // gold + (prod)[0][0]
        // Reset sync/accum state for next launch / graph replay.
        __hip_atomic_store(&g_gold, 0.f, __ATOMIC_RELAXED,
                           __HIP_MEMORY_SCOPE_AGENT);
        __hip_atomic_store(&g_done, 0, __ATOMIC_RELAXED,
                           __HIP_MEMORY_SCOPE_AGENT);
      }
    }
    if (t < 32)
      __hip_atomic_store(&g_cnt[t], 0, __ATOMIC_RELAXED,
                         __HIP_MEMORY_SCOPE_AGENT);
  }
}

extern "C" void kernel_launch(void* const* d_in, const int* in_sizes, int n_in,
                              void* d_out, int out_size, void* d_ws, size_t ws_size,
                              hipStream_t stream) {
  const float* emb = (const float*)d_in[0];
  const float* W1 = (const float*)d_in[1];
  const float* b1 = (const float*)d_in[2];
  const float* W2 = (const float*)d_in[3];
  const float* b2 = (const float*)d_in[4];
  float* out = (float*)d_out;
  hipLaunchKernelGGL(k_all, dim3(1024), dim3(256), 0, stream, emb, W1, b1, W2, b2, out);
}

// Round 3
// 110.141 us; speedup vs baseline: 1.3173x; 1.1509x over previous
//
#include <hip/hip_runtime.h>
#include <math.h>

#define NV 16385
#define NEDGE 131072
#define NEG -1e30f
#define SCALE 2.8853900817779268f  // 2*log2(e): tanh(x) = 1 - 2/(exp2(SCALE*x)+1)

typedef __attribute__((ext_vector_type(8))) short short8;
typedef __attribute__((ext_vector_type(4))) float f32x4;

// Scratch as static device globals. g_gold reset by k_tail2 each launch
// (.bss-zero on first launch) -> graph replays identical.
__device__ float g_part[4 * NEDGE];  // per-h-tile partial edge sums
__device__ float g_mats[32 * 64];    // 32 segment matrices (8x8, row-major)
__device__ float g_gold;             // gold-path sum
// Pre-formatted inputs (written by k_prep each launch):
//  g_embh: emb as bf16, row r = node v = r-8 (8 zero halo rows in front,
//  zero tail rows), each row's sixteen 16B-granules XOR-swizzled by
//  key(r) = (r-1)&7 so a LINEAR global_load_lds into LDS yields the
//  bank-conflict-free layout the MFMA ds_read_b128 wants.
__device__ unsigned short g_embh[16408 * 128];  // 4.2 MB
//  g_w1bf: W1 as bf16 in fragment order: granule gi = (f*4+hx)*256 + t
//  (f: 0-3 = fA[kc], 4-7 = fB[kc]) -> 8 coalesced dwordx4 loads per thread.
__device__ unsigned short g_w1bf[8192 * 8];     // 128 KB

__device__ __forceinline__ unsigned short f2bf(float x) {
  union { float f; unsigned int u; } c; c.f = x;
  unsigned int u = c.u;
  unsigned int r = (u + 0x7fffu + ((u >> 16) & 1u)) >> 16;  // RNE
  return (unsigned short)r;
}

__device__ __forceinline__ void gll16(const void* g, void* l) {
  // global -> LDS direct copy, 16B per lane. LDS dest is wave-uniform base
  // + lane*16 (per-lane l must be uniform across the wave); global src is
  // per-lane.
  __builtin_amdgcn_global_load_lds(
      (const __attribute__((address_space(1))) unsigned int*)g,
      (__attribute__((address_space(3))) unsigned int*)l, 16, 0, 0);
}

__device__ __forceinline__ float lse8(float x0, float x1, float x2, float x3,
                                      float x4, float x5, float x6, float x7) {
  float m = fmaxf(fmaxf(fmaxf(x0, x1), fmaxf(x2, x3)),
                  fmaxf(fmaxf(x4, x5), fmaxf(x6, x7)));
  float s = __expf(x0 - m) + __expf(x1 - m) + __expf(x2 - m) + __expf(x3 - m) +
            __expf(x4 - m) + __expf(x5 - m) + __expf(x6 - m) + __expf(x7 - m);
  return m + __logf(s);
}

// Full-wave 8x8 log-semiring matmul: lane l=(i*8+j) holds A[i][j], B[i][j];
// returns (A (X) B)[i][j] = lse_k(A[i][k] + B[k][j]).  A = later chunk.
__device__ __forceinline__ float comb8(float A, float B, int i8, int j) {
  float x0 = __shfl(A, i8 + 0) + __shfl(B, 0 + j);
  float x1 = __shfl(A, i8 + 1) + __shfl(B, 8 + j);
  float x2 = __shfl(A, i8 + 2) + __shfl(B, 16 + j);
  float x3 = __shfl(A, i8 + 3) + __shfl(B, 24 + j);
  float x4 = __shfl(A, i8 + 4) + __shfl(B, 32 + j);
  float x5 = __shfl(A, i8 + 5) + __shfl(B, 40 + j);
  float x6 = __shfl(A, i8 + 6) + __shfl(B, 48 + j);
  float x7 = __shfl(A, i8 + 7) + __shfl(B, 56 + j);
  return lse8(x0, x1, x2, x3, x4, x5, x6, x7);
}

// One edge-phase term with FACTORED exponential: ea/eb are exp2-domain values
// (ea*eb = exp2(2log2e*(A+B+b1))).  acc += w * rcp(ea*eb + 1); only 1 trans op.
#define ETERM(ea, eb, w, acc)                              \
  {                                                        \
    float e_ = (ea) * (eb);                                \
    acc = fmaf(__builtin_amdgcn_rcpf(e_ + 1.f), (w), acc); \
  }

// ---------------- k_prep: format emb + W1 for the producer ----------------
__global__ __launch_bounds__(256) void k_prep(const float* __restrict__ emb,
                                              const float* __restrict__ W1) {
  const int gid = blockIdx.x * 256 + threadIdx.x;
  // emb: 16408 rows x 16 granules of 16B; row r <- node v = r-8, swizzled.
  for (int i = gid; i < 16408 * 16; i += 256 * 256) {
    const int r = i >> 4, g = i & 15;
    const int key = (r - 1) & 7;
    const int v = r - 8;
    uint4 o = make_uint4(0u, 0u, 0u, 0u);
    if (v >= 0 && v < NV) {
      const float* src = &emb[v * 128 + ((g ^ key) << 3)];
      float4 a = *(const float4*)src;
      float4 b = *(const float4*)(src + 4);
      o.x = f2bf(a.x) | ((unsigned int)f2bf(a.y) << 16);
      o.y = f2bf(a.z) | ((unsigned int)f2bf(a.w) << 16);
      o.z = f2bf(b.x) | ((unsigned int)f2bf(b.y) << 16);
      o.w = f2bf(b.z) | ((unsigned int)f2bf(b.w) << 16);
    }
    *(uint4*)&g_embh[(r << 7) + (g << 3)] = o;
  }
  // W1 fragments: gi = (f*4+hx)*256 + t; element i of the short8 holds
  // f2bf(W1[(kb+i)*256 + col]) matching the producer's fA/fB pack order.
  if (gid < 8192) {
    const int tt = gid & 255;
    const int fh = gid >> 8;             // f*4 + hx, 0..31
    const int hx = fh & 3, f = fh >> 2;  // f 0..7
    const int wv = tt >> 6, lane = tt & 63;
    const int l15 = lane & 15, quad = lane >> 4;
    const int col = (hx << 6) + (wv << 4) + l15;
    const int kb = ((f & 3) << 5) + (quad << 3) + ((f >> 2) << 7);
    unsigned int w[4];
#pragma unroll
    for (int i = 0; i < 8; i += 2) {
      float a0 = W1[(kb + i) * 256 + col];
      float a1 = W1[(kb + i + 1) * 256 + col];
      w[i >> 1] = f2bf(a0) | ((unsigned int)f2bf(a1) << 16);
    }
    *(uint4*)&g_w1bf[gid << 3] = *(const uint4*)w;
  }
}

// ---------------- k12: projection + edge phase (producer) ----------------
// Grid (4 h-tiles, 256 node-tiles of 64), 256 thr, 4 blocks/CU (38.2KB LDS).
__global__ __launch_bounds__(256, 4) void k12_fused(const float* __restrict__ b1,
                                                    const float* __restrict__ W2) {
  __shared__ __align__(16) unsigned short lds[19088];  // 38176 B
  unsigned short* Es = lds;             // [80][128] bf16, XOR-swizzled rows
  float* CA = (float*)lds;              // [71][68] f32 EA (aliases Es)
  float* CB = (float*)(lds + 10240);    // [64][68] f32 EB   (byte 20480)
  float* W2s = (float*)(lds + 18944);   // [64] f32 (-2*W2)  (byte 37888)
  float* Wsum = (float*)(lds + 19072);  // [8] per-granule sum (byte 38144)

  const int t = threadIdx.x;
  const int hx = blockIdx.x;
  const int h0 = hx << 6;
  const int i0 = (int)blockIdx.y << 6;
  const int wv = t >> 6, lane = t & 63;
  const int l15 = lane & 15, quad = lane >> 4;

  // Stage 80 bf16 rows (20480 B) straight into LDS: 5 x global_load_lds of
  // 1KB/wave. Source is linear in g_embh (swizzle pre-baked); no VALU, no
  // VGPR roundtrip, no bounds branches (halo rows are pre-zeroed).
  {
    const char* src = (const char*)&g_embh[(i0 + 1) << 7];
    char* dst = (char*)lds;
#pragma unroll
    for (int p = 0; p < 5; ++p) {
      const int off = (p << 12) + (wv << 10);
      gll16(src + off + (lane << 4), dst + off);
    }
  }

  if (t < 64) W2s[t] = -2.f * W2[h0 + t];
  if (t < 8) {
    float s = 0.f;
#pragma unroll
    for (int jj = 0; jj < 8; ++jj) s += W2[h0 + (t << 3) + jj];
    Wsum[t] = s;
  }

  // W1 fragments: 8 coalesced 16B loads per thread from fragment-ordered bf16.
  short8 fA[4], fB[4];
#pragma unroll
  for (int kc = 0; kc < 4; ++kc) {
    fA[kc] = *(const short8*)&g_w1bf[((((kc << 2) + hx) << 8) + t) << 3];
    fB[kc] = *(const short8*)&g_w1bf[((((16 + (kc << 2)) + hx) << 8) + t) << 3];
  }

  f32x4 accA[5], accB[4];
#pragma unroll
  for (int m = 0; m < 5; ++m) accA[m] = (f32x4){0.f, 0.f, 0.f, 0.f};
#pragma unroll
  for (int m = 0; m < 4; ++m) accB[m] = (f32x4){0.f, 0.f, 0.f, 0.f};

  __syncthreads();  // global_load_lds drained (vmcnt) + all waves staged

  // A-frag reads undo the XOR: want shorts [cb, cb+8) of row -> read
  // cb ^ ((row&7)<<3). 16 rows/quad-group spread over all 8 granule slots
  // -> 2-way conflicts (free).
#pragma unroll
  for (int kc = 0; kc < 4; ++kc) {
    const int cb = (kc << 5) + (quad << 3);
#pragma unroll
    for (int mf = 0; mf < 5; ++mf) {
      const int row = (mf << 4) + l15;
      short8 a = *(const short8*)&Es[(row << 7) + (cb ^ ((row & 7) << 3))];
      accA[mf] = __builtin_amdgcn_mfma_f32_16x16x32_bf16(a, fA[kc], accA[mf], 0, 0, 0);
    }
#pragma unroll
    for (int mf = 0; mf < 4; ++mf) {
      const int row = 8 + (mf << 4) + l15;
      short8 a = *(const short8*)&Es[(row << 7) + (cb ^ ((row & 7) << 3))];
      accB[mf] = __builtin_amdgcn_mfma_f32_16x16x32_bf16(a, fB[kc], accB[mf], 0, 0, 0);
    }
  }
  __syncthreads();  // all MFMA reads of Es done before aliasing C over it
  // Store C tiles in exp2 domain: EA = exp2(SCALE*(A+b1)), EB = exp2(SCALE*B).
  // C/D frag: row = quad*4+reg, col = lane&15.  Pitch 68: 2-way (free).
  // CA region is only 71 rows now (rows >70 never read by the edge phase).
  const int hcol = (wv << 4) + l15;
  const float b1s = b1[h0 + hcol];
#pragma unroll
  for (int mf = 0; mf < 5; ++mf) {
    int rb = (mf << 4) + (quad << 2);
#pragma unroll
    for (int rr = 0; rr < 4; ++rr)
      if (rb + rr < 71)
        CA[(rb + rr) * 68 + hcol] =
            __builtin_amdgcn_exp2f((accA[mf][rr] + b1s) * SCALE);
  }
#pragma unroll
  for (int mf = 0; mf < 4; ++mf) {
    int rb = (mf << 4) + (quad << 2);
#pragma unroll
    for (int rr = 0; rr < 4; ++rr)
      CB[(rb + rr) * 68 + hcol] = __builtin_amdgcn_exp2f(accB[mf][rr] * SCALE);
  }
  __syncthreads();
  // Edge phase: thread t -> k = t&7, qb = t>>3; edges q = qb, qb+32.
  const int k = t & 7;
  const int qb = t >> 3;
  float ws_all = 0.f;
#pragma unroll
  for (int s = 0; s < 8; ++s) ws_all += Wsum[s];
  float pa0 = 0.f, pa1 = 0.f, pb0 = 0.f, pb1 = 0.f;
#pragma unroll
  for (int g = 0; g < 8; ++g) {
    const int s = (g + (k << 1)) & 7;  // granule rotation: uniform banks
    const float* wp = &W2s[s << 3];
    float4 w0 = *(const float4*)wp;
    float4 w1 = *(const float4*)(wp + 4);
    {
      const float* ap = &CA[(7 + qb - k) * 68 + (s << 3)];
      const float* bp = &CB[qb * 68 + (s << 3)];
      float4 a0 = *(const float4*)ap, a1 = *(const float4*)(ap + 4);
      float4 b0 = *(const float4*)bp, b1v = *(const float4*)(bp + 4);
      ETERM(a0.x, b0.x, w0.x, pa0); ETERM(a0.y, b0.y, w0.y, pa0);
      ETERM(a0.z, b0.z, w0.z, pa0); ETERM(a0.w, b0.w, w0.w, pa0);
      ETERM(a1.x, b1v.x, w1.x, pa1); ETERM(a1.y, b1v.y, w1.y, pa1);
      ETERM(a1.z, b1v.z, w1.z, pa1); ETERM(a1.w, b1v.w, w1.w, pa1);
    }
    {
      const int q = qb + 32;
      const float* ap = &CA[(7 + q - k) * 68 + (s << 3)];
      const float* bp = &CB[q * 68 + (s << 3)];
      float4 a0 = *(const float4*)ap, a1 = *(const float4*)(ap + 4);
      float4 b0 = *(const float4*)bp, b1v = *(const float4*)(bp + 4);
      ETERM(a0.x, b0.x, w0.x, pb0); ETERM(a0.y, b0.y, w0.y, pb0);
      ETERM(a0.z, b0.z, w0.z, pb0); ETERM(a0.w, b0.w, w0.w, pb0);
      ETERM(a1.x, b1v.x, w1.x, pb1); ETERM(a1.y, b1v.y, w1.y, pb1);
      ETERM(a1.z, b1v.z, w1.z, pb1); ETERM(a1.w, b1v.w, w1.w, pb1);
    }
  }
  const int ebase = hx * NEDGE + ((int)blockIdx.y << 9) + t;
  g_part[ebase] = (pa0 + pa1) + ws_all;
  g_part[ebase + 256] = (pb0 + pb1) + ws_all;
}

// K_tail1: 32 blocks x 256. Block b: edges [b*4096,(b+1)*4096) -> softplus +
// gold (wave-shuffle + atomicAdd) + 8 chunk recurrences -> 1 segment matrix.
// NO fences, NO tickets — the kernel boundary publishes g_mats/g_gold.
__global__ __launch_bounds__(256) void k_tail1(const float* __restrict__ b2) {
  __shared__ float wf[64][64];   // [step][chunk_local*8 + k]
  __shared__ float m8[8][64];    // 8 chunk matrices
  const int t = threadIdx.x;
  const int b = blockIdx.x;
  const float b2v = b2[0];
  float gold = 0.f;
#pragma unroll
  for (int it = 0; it < 4; ++it) {
    const int e4 = t + (it << 8);
    const int gidx = (b << 10) + e4;
    float4 s0 = *(const float4*)&g_part[gidx << 2];
    float4 s1 = *(const float4*)&g_part[NEDGE + (gidx << 2)];
    float4 s2 = *(const float4*)&g_part[2 * NEDGE + (gidx << 2)];
    float4 s3 = *(const float4*)&g_part[3 * NEDGE + (gidx << 2)];
    float d0 = s0.x + s1.x + s2.x + s3.x + b2v;
    float d1 = s0.y + s1.y + s2.y + s3.y + b2v;
    float d2 = s0.z + s1.z + s2.z + s3.z + b2v;
    float d3 = s0.w + s1.w + s2.w + s3.w + b2v;
    d0 = fmaxf(d0, 0.f) + log1pf(__expf(-fabsf(d0)));
    d1 = fmaxf(d1, 0.f) + log1pf(__expf(-fabsf(d1)));
    d2 = fmaxf(d2, 0.f) + log1pf(__expf(-fabsf(d2)));
    d3 = fmaxf(d3, 0.f) + log1pf(__expf(-fabsf(d3)));
    const int q = e4 << 2;
    const int cl = q >> 9, r = q & 511;
    const int s = r >> 3, kk = r & 7;
    *(float4*)&wf[s][(cl << 3) + kk] = make_float4(d0, d1, d2, d3);
    if ((t & 1) == 0) gold += d0;  // k==0 edges (gold path)
  }
  // Gold: butterfly within wave, one atomic per wave (4/block, 128 total).
#pragma unroll
  for (int off = 32; off > 0; off >>= 1) gold += __shfl_xor(gold, off, 64);
  if ((t & 63) == 0) atomicAdd(&g_gold, gold);
  __syncthreads();
  if (b == 0 && t == 0) {
    // node i = s+1 has valid preds kk <= s only: poison invalid d with +1e30
    for (int s = 0; s < 7; ++s)
      for (int kk = s + 1; kk < 8; ++kk) wf[s][kk] = 1e30f;
  }
  __syncthreads();
  if (t < 64) {  // wave 0: 8 chunk recurrences (8 lanes each)
    const int g = t >> 3, j = t & 7;
    float P[8];
#pragma unroll
    for (int kk = 0; kk < 8; ++kk) P[kk] = (kk == j) ? 0.f : NEG;
    for (int s = 0; s < 64; ++s) {
      const float* wp = &wf[s][g << 3];
      float4 wa = *(const float4*)wp;
      float4 wb = *(const float4*)(wp + 4);
      float nv = lse8(P[0] - wa.x, P[1] - wa.y, P[2] - wa.z, P[3] - wa.w,
                      P[4] - wb.x, P[5] - wb.y, P[6] - wb.z, P[7] - wb.w);
#pragma unroll
      for (int kk = 7; kk > 0; --kk) P[kk] = P[kk - 1];
      P[0] = nv;
    }
#pragma unroll
    for (int kk = 0; kk < 8; ++kk) m8[g][(kk << 3) + j] = P[kk];  // row-major
    // Combine 8 chunk mats -> segment mat (in-wave, DS ops in-order).
    const int i8 = (t >> 3) << 3;
    float R = m8[0][t];
#pragma unroll
    for (int g2 = 1; g2 < 8; ++g2) R = comb8(m8[g2][t], R, i8, j);
    g_mats[(b << 6) + t] = R;
  }
}

// K_tail2: 1 block x 256. Final combine of 32 segment matrices + out + reset.
__global__ __launch_bounds__(256) void k_tail2(float* __restrict__ out) {
  __shared__ float l2m[4][64];
  const int t = threadIdx.x;
  const int l = t & 63, w = t >> 6;
  const int i8 = (l >> 3) << 3, j = l & 7;
  float G = g_mats[((w << 3) << 6) + l];
#pragma unroll
  for (int s2 = 1; s2 < 8; ++s2)
    G = comb8(g_mats[(((w << 3) + s2) << 6) + l], G, i8, j);
  l2m[w][l] = G;
  __syncthreads();
  if (t < 64) {
    float G2 = l2m[0][t];
#pragma unroll
    for (int w2 = 1; w2 < 4; ++w2) G2 = comb8(l2m[w2][t], G2, i8, j);
    if (t == 0) {
      out[0] = g_gold + G2;  // gold + (prod)[0][0]
      g_gold = 0.f;          // reset for next launch / graph replay
    }
  }
}

extern "C" void kernel_launch(void* const* d_in, const int* in_sizes, int n_in,
                              void* d_out, int out_size, void* d_ws, size_t ws_size,
                              hipStream_t stream) {
  const float* emb = (const float*)d_in[0];
  const float* W1 = (const float*)d_in[1];
  const float* b1 = (const float*)d_in[2];
  const float* W2 = (const float*)d_in[3];
  const float* b2 = (const float*)d_in[4];
  float* out = (float*)d_out;
  hipLaunchKernelGGL(k_prep, dim3(256), dim3(256), 0, stream, emb, W1);
  hipLaunchKernelGGL(k12_fused, dim3(4, 256), dim3(256), 0, stream, b1, W2);
  hipLaunchKernelGGL(k_tail1, dim3(32), dim3(256), 0, stream, b2);
  hipLaunchKernelGGL(k_tail2, dim3(1), dim3(256), 0, stream, out);
}